// Round 8
// baseline (1788.863 us; speedup 1.0000x reference)
//
#include <hip/hip_runtime.h>

// GCN: 3x (linear(bf16 msg out) -> bucket-aggregate(LDS f32 acc) -> bias+act).
// N=100000, E=1600000, IN=128, HID=OUT=64.
// R6: coarse-bucket binning (511 buckets x 196 nodes) replaces per-node CSR;
//     bf16 message buffer halves gather traffic; LDS-atomic accumulation.

#define FOUT 64
#define NPB2 196          // dst nodes per bucket (196*64*4B = 50.2KB LDS acc)
#define NBUCKET 511       // ceil(100000/196)
#define CAP 4096          // records per bucket (mean 3131, +17 sigma)
#define CHUNK 8192        // edges per bin-block

// ---------------- helpers ----------------
__device__ __forceinline__ unsigned short f2bf(float f) {
    unsigned u = __float_as_uint(f);
    u += 0x7FFF + ((u >> 16) & 1);          // round-to-nearest-even
    return (unsigned short)(u >> 16);
}
__device__ __forceinline__ float bf2f(unsigned short b) {
    return __uint_as_float(((unsigned)b) << 16);
}

// ---------------- dense linear (f32 in, bf16 out) ----------------
// Register-tiled: 256 thr = 4 waves, 64 rows/block, full K staged in LDS.
// Thread owns 4 features x 4 rows; W and x both read as ds_read_b128.
template<int K>
__global__ __launch_bounds__(256) void k_linear(
    const float* __restrict__ in, const float* __restrict__ W,
    unsigned short* __restrict__ outbf, int n) {
    constexpr int XSTR = (K == 128) ? 132 : 68;
    __shared__ float4 sW4[K * 16];
    __shared__ float xs[64 * XSTR];

    const int t = threadIdx.x;
    const int base = blockIdx.x * 64;

    const float4* W4 = (const float4*)W;
#pragma unroll
    for (int i = 0; i < K * 16 / 256; ++i) sW4[t + i * 256] = W4[t + i * 256];

    constexpr int CPR = K / 4;
#pragma unroll
    for (int i = 0; i < 64 * CPR / 256; ++i) {
        int flat = t + i * 256;
        int row = flat / CPR;
        int c4 = flat % CPR;
        int rg = base + row;
        if (rg < n) {
            float4 v = *(const float4*)(in + (size_t)rg * K + c4 * 4);
            *(float4*)&xs[row * XSTR + c4 * 4] = v;
        }
    }
    __syncthreads();

    const int fq = t & 15;
    const int slot = (t >> 4) & 3;
    const int wave = t >> 6;
    const int r0 = wave * 16 + slot * 4;

    float4 acc[4];
#pragma unroll
    for (int i = 0; i < 4; ++i) acc[i] = make_float4(0.f, 0.f, 0.f, 0.f);

#pragma unroll 8
    for (int k = 0; k < K; k += 4) {
        float4 w0 = sW4[(k + 0) * 16 + fq];
        float4 w1 = sW4[(k + 1) * 16 + fq];
        float4 w2 = sW4[(k + 2) * 16 + fq];
        float4 w3 = sW4[(k + 3) * 16 + fq];
#pragma unroll
        for (int i = 0; i < 4; ++i) {
            float4 xv = *(const float4*)&xs[(r0 + i) * XSTR + k];
            acc[i].x = fmaf(xv.x, w0.x, acc[i].x);
            acc[i].y = fmaf(xv.x, w0.y, acc[i].y);
            acc[i].z = fmaf(xv.x, w0.z, acc[i].z);
            acc[i].w = fmaf(xv.x, w0.w, acc[i].w);
            acc[i].x = fmaf(xv.y, w1.x, acc[i].x);
            acc[i].y = fmaf(xv.y, w1.y, acc[i].y);
            acc[i].z = fmaf(xv.y, w1.z, acc[i].z);
            acc[i].w = fmaf(xv.y, w1.w, acc[i].w);
            acc[i].x = fmaf(xv.z, w2.x, acc[i].x);
            acc[i].y = fmaf(xv.z, w2.y, acc[i].y);
            acc[i].z = fmaf(xv.z, w2.z, acc[i].z);
            acc[i].w = fmaf(xv.z, w2.w, acc[i].w);
            acc[i].x = fmaf(xv.w, w3.x, acc[i].x);
            acc[i].y = fmaf(xv.w, w3.y, acc[i].y);
            acc[i].z = fmaf(xv.w, w3.z, acc[i].z);
            acc[i].w = fmaf(xv.w, w3.w, acc[i].w);
        }
    }

#pragma unroll
    for (int i = 0; i < 4; ++i) {
        int rg = base + r0 + i;
        if (rg < n) {
            ushort4 us;
            us.x = f2bf(acc[i].x); us.y = f2bf(acc[i].y);
            us.z = f2bf(acc[i].z); us.w = f2bf(acc[i].w);
            *(ushort4*)(outbf + (size_t)rg * FOUT + fq * 4) = us;
        }
    }
}

// ---------------- bucket binning ----------------
__global__ __launch_bounds__(512) void k_init(int* __restrict__ gcursor) {
    gcursor[threadIdx.x] = threadIdx.x * CAP;
}

// One block per CHUNK of edges: LDS histogram over NBUCKET buckets ->
// one global cursor reservation per bucket -> direct scatter. Each output
// cache line is written by exactly one block (no cross-XCD line sharing).
__global__ __launch_bounds__(256) void k_bin(
    const int* __restrict__ src, const int* __restrict__ dst,
    int* __restrict__ gcursor, int* __restrict__ bins, int ne) {
    __shared__ int cnt[NBUCKET];
    __shared__ int gbase[NBUCKET];

    const int t = threadIdx.x;
    const int cbeg = blockIdx.x * CHUNK;
    const int cend = min(cbeg + CHUNK, ne);

    for (int i = t; i < NBUCKET; i += 256) cnt[i] = 0;
    __syncthreads();

    for (int e = cbeg + t; e < cend; e += 256)
        atomicAdd(&cnt[dst[e] / NPB2], 1);
    __syncthreads();

    for (int i = t; i < NBUCKET; i += 256) {
        int c = cnt[i];
        gbase[i] = (c > 0) ? atomicAdd(&gcursor[i], c) : 0;
    }
    __syncthreads();
    for (int i = t; i < NBUCKET; i += 256) cnt[i] = 0;   // reuse as local cursor
    __syncthreads();

    for (int e = cbeg + t; e < cend; e += 256) {
        int d = dst[e];
        int b = d / NPB2;
        int dl = d - b * NPB2;
        int lpos = atomicAdd(&cnt[b], 1);
        int gpos = gbase[b] + lpos;
        // capacity guard (never hit for this fixed graph; protects memory)
        if (gpos < (b + 1) * CAP)
            bins[gpos] = src[e] | (dl << 17);
    }
}

// ---------------- bucket aggregation ----------------
// One block per bucket (196 nodes, 50KB LDS f32 accumulator, 8 waves).
// Wave processes 4 edges/iter: broadcast int4 record load, bf16 gather
// (lane = feature), ds_add_f32 accumulate. Bias+act fused epilogue.
// ACT: 0 = ReLU, 1 = sigmoid.
template<int ACT>
__global__ __launch_bounds__(512) void k_agg_bucket(
    const int* __restrict__ gcursor, const int* __restrict__ bins,
    const unsigned short* __restrict__ msg, const float* __restrict__ bias,
    float* __restrict__ out, int n) {
    __shared__ float accS[NPB2 * FOUT];

    const int t = threadIdx.x;
    const int lane = t & 63;
    const int wid = t >> 6;
    const int b = blockIdx.x;

    for (int i = t; i < NPB2 * FOUT; i += 512) accS[i] = 0.f;

    const int cnt = gcursor[b] - b * CAP;
    const int* recs = bins + b * CAP;
    const float bv = bias[lane];
    __syncthreads();

    for (int base = wid * 4; base < cnt; base += 32) {
        if (base + 4 <= cnt) {
            int4 r4 = *(const int4*)(recs + base);
            unsigned r0 = (unsigned)r4.x, r1 = (unsigned)r4.y;
            unsigned r2 = (unsigned)r4.z, r3 = (unsigned)r4.w;
            float v0 = bf2f(msg[(size_t)(r0 & 0x1FFFF) * FOUT + lane]);
            float v1 = bf2f(msg[(size_t)(r1 & 0x1FFFF) * FOUT + lane]);
            float v2 = bf2f(msg[(size_t)(r2 & 0x1FFFF) * FOUT + lane]);
            float v3 = bf2f(msg[(size_t)(r3 & 0x1FFFF) * FOUT + lane]);
            atomicAdd(&accS[(r0 >> 17) * FOUT + lane], v0);
            atomicAdd(&accS[(r1 >> 17) * FOUT + lane], v1);
            atomicAdd(&accS[(r2 >> 17) * FOUT + lane], v2);
            atomicAdd(&accS[(r3 >> 17) * FOUT + lane], v3);
        } else {
            for (int j = base; j < cnt; ++j) {
                unsigned r = (unsigned)recs[j];
                float v = bf2f(msg[(size_t)(r & 0x1FFFF) * FOUT + lane]);
                atomicAdd(&accS[(r >> 17) * FOUT + lane], v);
            }
        }
    }
    __syncthreads();

    const int node0 = b * NPB2;
    for (int i = wid; i < NPB2; i += 8) {
        int node = node0 + i;
        if (node < n) {
            float v = accS[i * FOUT + lane] + bv;
            out[(size_t)node * FOUT + lane] =
                (ACT == 0) ? fmaxf(v, 0.f) : 1.f / (1.f + __expf(-v));
        }
    }
}

extern "C" void kernel_launch(void* const* d_in, const int* in_sizes, int n_in,
                              void* d_out, int out_size, void* d_ws, size_t ws_size,
                              hipStream_t stream) {
    const float* x  = (const float*)d_in[0];
    const int*   ei = (const int*)d_in[1];
    const float* W1 = (const float*)d_in[2];
    const float* b1 = (const float*)d_in[3];
    const float* W2 = (const float*)d_in[4];
    const float* b2 = (const float*)d_in[5];
    const float* W3 = (const float*)d_in[6];
    const float* b3 = (const float*)d_in[7];
    float* out = (float*)d_out;

    const int n  = in_sizes[0] / 128;   // 100000
    const int ne = in_sizes[1] / 2;     // 1600000
    const int* src = ei;
    const int* dst = ei + ne;

    const size_t feat_elems = (size_t)n * FOUT;

    // workspace layout
    unsigned short* msg16 = (unsigned short*)d_ws;              // n*64 bf16 (12.8MB)
    float* B      = (float*)(msg16 + feat_elems);               // n*64 f32  (25.6MB)
    int*   bins   = (int*)(B + feat_elems);                     // 511*4096  (8.4MB)
    int*   gcursor = bins + (size_t)NBUCKET * CAP;              // 511

    const int gLin = (n + 63) / 64;
    const int gBin = (ne + CHUNK - 1) / CHUNK;   // 196

    // ---- bucket binning (every call: ws is re-poisoned) ----
    k_init<<<1, NBUCKET, 0, stream>>>(gcursor);
    k_bin<<<gBin, 256, 0, stream>>>(src, dst, gcursor, bins, ne);

    // ---- Layer 1 ----
    k_linear<128><<<gLin, 256, 0, stream>>>(x, W1, msg16, n);
    k_agg_bucket<0><<<NBUCKET, 512, 0, stream>>>(gcursor, bins, msg16, b1, B, n);
    // ---- Layer 2 ----
    k_linear<64><<<gLin, 256, 0, stream>>>(B, W2, msg16, n);
    k_agg_bucket<0><<<NBUCKET, 512, 0, stream>>>(gcursor, bins, msg16, b2, B, n);
    // ---- Layer 3 ----
    k_linear<64><<<gLin, 256, 0, stream>>>(B, W3, msg16, n);
    k_agg_bucket<1><<<NBUCKET, 512, 0, stream>>>(gcursor, bins, msg16, b3, out, n);
}

// Round 9
// 403.812 us; speedup vs baseline: 4.4299x; 4.4299x over previous
//
#include <hip/hip_runtime.h>

// GCN: 3x (linear(bf16 msg) -> per-node CSR gather-reduce -> bias+act).
// N=100000, E=1600000, IN=128, HID=OUT=64.
// R9: wide per-node aggregation (1 wave/node, latency-hidden) + bf16 msg;
//     CSR built via coarse-bucket binning + per-bucket LDS sort (no write-amp).

#define FOUT 64
#define NPB2 196          // dst nodes per bucket
#define NBUCKET 511       // ceil(100000/196)
#define CAP 4096          // records per bucket (mean 3131)
#define CHUNK 8192        // edges per bin-block

// ---------------- helpers ----------------
__device__ __forceinline__ unsigned short f2bf(float f) {
    unsigned u = __float_as_uint(f);
    u += 0x7FFF + ((u >> 16) & 1);          // round-to-nearest-even
    return (unsigned short)(u >> 16);
}
__device__ __forceinline__ float bf2f(unsigned short b) {
    return __uint_as_float(((unsigned)b) << 16);
}

// ---------------- dense linear (f32 in, bf16 out) ----------------
// Register-tiled: 256 thr = 4 waves, 64 rows/block, full K staged in LDS.
// Thread owns 4 features x 4 rows; W and x both read as ds_read_b128.
template<int K>
__global__ __launch_bounds__(256) void k_linear(
    const float* __restrict__ in, const float* __restrict__ W,
    unsigned short* __restrict__ outbf, int n) {
    constexpr int XSTR = (K == 128) ? 132 : 68;
    __shared__ float4 sW4[K * 16];
    __shared__ float xs[64 * XSTR];

    const int t = threadIdx.x;
    const int base = blockIdx.x * 64;

    const float4* W4 = (const float4*)W;
#pragma unroll
    for (int i = 0; i < K * 16 / 256; ++i) sW4[t + i * 256] = W4[t + i * 256];

    constexpr int CPR = K / 4;
#pragma unroll
    for (int i = 0; i < 64 * CPR / 256; ++i) {
        int flat = t + i * 256;
        int row = flat / CPR;
        int c4 = flat % CPR;
        int rg = base + row;
        if (rg < n) {
            float4 v = *(const float4*)(in + (size_t)rg * K + c4 * 4);
            *(float4*)&xs[row * XSTR + c4 * 4] = v;
        }
    }
    __syncthreads();

    const int fq = t & 15;
    const int slot = (t >> 4) & 3;
    const int wave = t >> 6;
    const int r0 = wave * 16 + slot * 4;

    float4 acc[4];
#pragma unroll
    for (int i = 0; i < 4; ++i) acc[i] = make_float4(0.f, 0.f, 0.f, 0.f);

#pragma unroll 8
    for (int k = 0; k < K; k += 4) {
        float4 w0 = sW4[(k + 0) * 16 + fq];
        float4 w1 = sW4[(k + 1) * 16 + fq];
        float4 w2 = sW4[(k + 2) * 16 + fq];
        float4 w3 = sW4[(k + 3) * 16 + fq];
#pragma unroll
        for (int i = 0; i < 4; ++i) {
            float4 xv = *(const float4*)&xs[(r0 + i) * XSTR + k];
            acc[i].x = fmaf(xv.x, w0.x, acc[i].x);
            acc[i].y = fmaf(xv.x, w0.y, acc[i].y);
            acc[i].z = fmaf(xv.x, w0.z, acc[i].z);
            acc[i].w = fmaf(xv.x, w0.w, acc[i].w);
            acc[i].x = fmaf(xv.y, w1.x, acc[i].x);
            acc[i].y = fmaf(xv.y, w1.y, acc[i].y);
            acc[i].z = fmaf(xv.y, w1.z, acc[i].z);
            acc[i].w = fmaf(xv.y, w1.w, acc[i].w);
            acc[i].x = fmaf(xv.z, w2.x, acc[i].x);
            acc[i].y = fmaf(xv.z, w2.y, acc[i].y);
            acc[i].z = fmaf(xv.z, w2.z, acc[i].z);
            acc[i].w = fmaf(xv.z, w2.w, acc[i].w);
            acc[i].x = fmaf(xv.w, w3.x, acc[i].x);
            acc[i].y = fmaf(xv.w, w3.y, acc[i].y);
            acc[i].z = fmaf(xv.w, w3.z, acc[i].z);
            acc[i].w = fmaf(xv.w, w3.w, acc[i].w);
        }
    }

#pragma unroll
    for (int i = 0; i < 4; ++i) {
        int rg = base + r0 + i;
        if (rg < n) {
            ushort4 us;
            us.x = f2bf(acc[i].x); us.y = f2bf(acc[i].y);
            us.z = f2bf(acc[i].z); us.w = f2bf(acc[i].w);
            *(ushort4*)(outbf + (size_t)rg * FOUT + fq * 4) = us;
        }
    }
}

// ---------------- bucket binning ----------------
__global__ __launch_bounds__(512) void k_init(int* __restrict__ gcursor) {
    gcursor[threadIdx.x] = threadIdx.x * CAP;
}

// One block per CHUNK of edges: LDS histogram over NBUCKET buckets ->
// one global cursor reservation per bucket -> direct scatter. Each output
// line written by exactly one block (no cross-XCD write sharing).
__global__ __launch_bounds__(256) void k_bin(
    const int* __restrict__ src, const int* __restrict__ dst,
    int* __restrict__ gcursor, int* __restrict__ bins, int ne) {
    __shared__ int cnt[NBUCKET];
    __shared__ int gbase[NBUCKET];

    const int t = threadIdx.x;
    const int cbeg = blockIdx.x * CHUNK;
    const int cend = min(cbeg + CHUNK, ne);

    for (int i = t; i < NBUCKET; i += 256) cnt[i] = 0;
    __syncthreads();

    for (int e = cbeg + t; e < cend; e += 256)
        atomicAdd(&cnt[dst[e] / NPB2], 1);
    __syncthreads();

    for (int i = t; i < NBUCKET; i += 256) {
        int c = cnt[i];
        gbase[i] = (c > 0) ? atomicAdd(&gcursor[i], c) : 0;
    }
    __syncthreads();
    for (int i = t; i < NBUCKET; i += 256) cnt[i] = 0;   // reuse as local cursor
    __syncthreads();

    for (int e = cbeg + t; e < cend; e += 256) {
        int d = dst[e];
        int b = d / NPB2;
        int dl = d - b * NPB2;
        int lpos = atomicAdd(&cnt[b], 1);
        int gpos = gbase[b] + lpos;
        if (gpos < (b + 1) * CAP)          // capacity guard (never hit here)
            bins[gpos] = src[e] | (dl << 17);
    }
}

// Exclusive scan of bucket counts -> bucket_base (records, global).
__global__ __launch_bounds__(512) void k_bscan(
    const int* __restrict__ gcursor, int* __restrict__ bucket_base) {
    __shared__ int s[512];
    const int t = threadIdx.x;
    int c = 0;
    if (t < NBUCKET) c = min(gcursor[t] - t * CAP, CAP);
    s[t] = c;
    __syncthreads();
    for (int ofs = 1; ofs < 512; ofs <<= 1) {
        int v = (t >= ofs) ? s[t - ofs] : 0;
        __syncthreads();
        s[t] += v;
        __syncthreads();
    }
    if (t < NBUCKET) bucket_base[t] = s[t] - c;
}

// Per-bucket LDS sort into per-node CSR. One block per bucket: stage the
// bucket's records in LDS, per-node histogram + local scan, scatter src
// into the bucket's CONTIGUOUS csr_src range (dense writes, no write-amp).
__global__ __launch_bounds__(256) void k_csr(
    const int* __restrict__ gcursor, const int* __restrict__ bins,
    const int* __restrict__ bucket_base, int* __restrict__ row_ofs,
    int* __restrict__ csr_src, int n) {
    __shared__ int recs[CAP];
    __shared__ int cnt[NPB2];
    __shared__ int ofs[NPB2];
    __shared__ int cur[NPB2];
    __shared__ int sscan[256];

    const int t = threadIdx.x;
    const int b = blockIdx.x;
    const int c = min(gcursor[b] - b * CAP, CAP);
    const int baseg = bucket_base[b];

    for (int i = t; i < c; i += 256) recs[i] = bins[b * CAP + i];
    for (int i = t; i < NPB2; i += 256) cnt[i] = 0;
    __syncthreads();

    for (int i = t; i < c; i += 256)
        atomicAdd(&cnt[((unsigned)recs[i]) >> 17], 1);
    __syncthreads();

    // exclusive scan of 196 counts (Hillis-Steele over 256 lanes)
    int v = (t < NPB2) ? cnt[t] : 0;
    sscan[t] = v;
    __syncthreads();
    for (int o = 1; o < 256; o <<= 1) {
        int u = (t >= o) ? sscan[t - o] : 0;
        __syncthreads();
        sscan[t] += u;
        __syncthreads();
    }
    if (t < NPB2) {
        ofs[t] = sscan[t] - v;
        cur[t] = sscan[t] - v;
        int node = b * NPB2 + t;
        if (node <= n) row_ofs[node] = baseg + ofs[t];
    }
    // nodes at bucket boundary are covered by next bucket's t=0 (ofs=0);
    // row_ofs[n] lands in the last bucket at t = n - b*NPB2 (ofs[t] == c there).
    __syncthreads();

    for (int i = t; i < c; i += 256) {
        unsigned r = (unsigned)recs[i];
        int dl = r >> 17;
        int p = atomicAdd(&cur[dl], 1);
        csr_src[baseg + p] = (int)(r & 0x1FFFF);
    }
}

// ---------------- aggregation (wide gather-reduce) ----------------
// One wave per node; lane = feature. bf16 gathers (128 B/edge), 4-deep
// load pipeline. Bias + activation fused. ACT: 0 = ReLU, 1 = sigmoid.
template<int ACT>
__global__ __launch_bounds__(256) void k_agg(
    const int* __restrict__ row_ofs, const int* __restrict__ csr_src,
    const unsigned short* __restrict__ msg, const float* __restrict__ bias,
    float* __restrict__ out, int n) {
    const int node = blockIdx.x * 4 + (threadIdx.x >> 6);
    if (node >= n) return;
    const int lane = threadIdx.x & 63;
    const int beg = row_ofs[node];
    const int end = row_ofs[node + 1];
    float acc = 0.f;
    int j = beg;
    for (; j + 4 <= end; j += 4) {
        int s0 = csr_src[j];
        int s1 = csr_src[j + 1];
        int s2 = csr_src[j + 2];
        int s3 = csr_src[j + 3];
        float v0 = bf2f(msg[(size_t)s0 * FOUT + lane]);
        float v1 = bf2f(msg[(size_t)s1 * FOUT + lane]);
        float v2 = bf2f(msg[(size_t)s2 * FOUT + lane]);
        float v3 = bf2f(msg[(size_t)s3 * FOUT + lane]);
        acc += (v0 + v1) + (v2 + v3);
    }
    for (; j < end; ++j)
        acc += bf2f(msg[(size_t)csr_src[j] * FOUT + lane]);
    float v = acc + bias[lane];
    out[(size_t)node * FOUT + lane] =
        (ACT == 0) ? fmaxf(v, 0.f) : 1.f / (1.f + __expf(-v));
}

extern "C" void kernel_launch(void* const* d_in, const int* in_sizes, int n_in,
                              void* d_out, int out_size, void* d_ws, size_t ws_size,
                              hipStream_t stream) {
    const float* x  = (const float*)d_in[0];
    const int*   ei = (const int*)d_in[1];
    const float* W1 = (const float*)d_in[2];
    const float* b1 = (const float*)d_in[3];
    const float* W2 = (const float*)d_in[4];
    const float* b2 = (const float*)d_in[5];
    const float* W3 = (const float*)d_in[6];
    const float* b3 = (const float*)d_in[7];
    float* out = (float*)d_out;

    const int n  = in_sizes[0] / 128;   // 100000
    const int ne = in_sizes[1] / 2;     // 1600000
    const int* src = ei;
    const int* dst = ei + ne;

    const size_t feat_elems = (size_t)n * FOUT;

    // workspace layout
    unsigned short* msg16 = (unsigned short*)d_ws;              // 12.8MB
    float* B        = (float*)(msg16 + feat_elems);             // 25.6MB
    int*   bins     = (int*)(B + feat_elems);                   // 8.4MB
    int*   gcursor  = bins + (size_t)NBUCKET * CAP;             // 511
    int*   bucket_base = gcursor + 512;                         // 512
    int*   row_ofs  = bucket_base + 512;                        // n+1
    int*   csr_src  = row_ofs + n + 1;                          // ne

    const int gLin = (n + 63) / 64;
    const int gBin = (ne + CHUNK - 1) / CHUNK;   // 196
    const int gAgg = (n + 3) / 4;                // 25000

    // ---- CSR build (every call: ws is re-poisoned) ----
    k_init<<<1, NBUCKET, 0, stream>>>(gcursor);
    k_bin<<<gBin, 256, 0, stream>>>(src, dst, gcursor, bins, ne);
    k_bscan<<<1, 512, 0, stream>>>(gcursor, bucket_base);
    k_csr<<<NBUCKET, 256, 0, stream>>>(gcursor, bins, bucket_base, row_ofs, csr_src, n);

    // ---- Layer 1 ----
    k_linear<128><<<gLin, 256, 0, stream>>>(x, W1, msg16, n);
    k_agg<0><<<gAgg, 256, 0, stream>>>(row_ofs, csr_src, msg16, b1, B, n);
    // ---- Layer 2 ----
    k_linear<64><<<gLin, 256, 0, stream>>>(B, W2, msg16, n);
    k_agg<0><<<gAgg, 256, 0, stream>>>(row_ofs, csr_src, msg16, b2, B, n);
    // ---- Layer 3 ----
    k_linear<64><<<gLin, 256, 0, stream>>>(B, W3, msg16, n);
    k_agg<1><<<gAgg, 256, 0, stream>>>(row_ofs, csr_src, msg16, b3, out, n);
}

// Round 10
// 376.413 us; speedup vs baseline: 4.7524x; 1.0728x over previous
//
#include <hip/hip_runtime.h>

// GCN: 3x (linear(bf16 msg) -> per-node CSR gather-reduce -> bias+act).
// N=100000, E=1600000, IN=128, HID=OUT=64.
// R10: k_agg gathers 2 edges per uint load (lane = feature-pair, half = edge),
//      shfl_xor(32) combine; inter-layer activations kept in bf16.

#define FOUT 64
#define NPB2 196          // dst nodes per bucket
#define NBUCKET 511       // ceil(100000/196)
#define CAP 4096          // records per bucket (mean 3131)
#define CHUNK 8192        // edges per bin-block

// ---------------- helpers ----------------
__device__ __forceinline__ unsigned short f2bf(float f) {
    unsigned u = __float_as_uint(f);
    u += 0x7FFF + ((u >> 16) & 1);          // round-to-nearest-even
    return (unsigned short)(u >> 16);
}
__device__ __forceinline__ float bflo(unsigned u) {   // low bf16 of a uint
    return __uint_as_float(u << 16);
}
__device__ __forceinline__ float bfhi(unsigned u) {   // high bf16 of a uint
    return __uint_as_float(u & 0xFFFF0000u);
}

// ---------------- dense linear (f32|bf16 in, bf16 out) ----------------
// Register-tiled: 256 thr = 4 waves, 64 rows/block, full K staged in LDS.
// Thread owns 4 features x 4 rows; W and x both read as ds_read_b128.
template<int K, int INBF>
__global__ __launch_bounds__(256) void k_linear(
    const void* __restrict__ inv, const float* __restrict__ W,
    unsigned short* __restrict__ outbf, int n) {
    constexpr int XSTR = (K == 128) ? 132 : 68;
    __shared__ float4 sW4[K * 16];
    __shared__ float xs[64 * XSTR];

    const int t = threadIdx.x;
    const int base = blockIdx.x * 64;

    const float4* W4 = (const float4*)W;
#pragma unroll
    for (int i = 0; i < K * 16 / 256; ++i) sW4[t + i * 256] = W4[t + i * 256];

    if (INBF) {
        // bf16 input: row = K bf16; load uint4 (8 bf16), convert, store f32.
        const unsigned short* in16 = (const unsigned short*)inv;
        constexpr int QPR = K / 8;                    // uint4 per row
#pragma unroll
        for (int i = 0; i < 64 * QPR / 256; ++i) {
            int flat = t + i * 256;
            int row = flat / QPR;
            int q = flat % QPR;
            int rg = base + row;
            if (rg < n) {
                uint4 u = *(const uint4*)(in16 + (size_t)rg * K + q * 8);
                float* xp = &xs[row * XSTR + q * 8];
                float4 a, b;
                a.x = bflo(u.x); a.y = bfhi(u.x);
                a.z = bflo(u.y); a.w = bfhi(u.y);
                b.x = bflo(u.z); b.y = bfhi(u.z);
                b.z = bflo(u.w); b.w = bfhi(u.w);
                *(float4*)(xp) = a;
                *(float4*)(xp + 4) = b;
            }
        }
    } else {
        const float* in = (const float*)inv;
        constexpr int CPR = K / 4;                    // float4 per row
#pragma unroll
        for (int i = 0; i < 64 * CPR / 256; ++i) {
            int flat = t + i * 256;
            int row = flat / CPR;
            int c4 = flat % CPR;
            int rg = base + row;
            if (rg < n) {
                float4 v = *(const float4*)(in + (size_t)rg * K + c4 * 4);
                *(float4*)&xs[row * XSTR + c4 * 4] = v;
            }
        }
    }
    __syncthreads();

    const int fq = t & 15;
    const int slot = (t >> 4) & 3;
    const int wave = t >> 6;
    const int r0 = wave * 16 + slot * 4;

    float4 acc[4];
#pragma unroll
    for (int i = 0; i < 4; ++i) acc[i] = make_float4(0.f, 0.f, 0.f, 0.f);

#pragma unroll 8
    for (int k = 0; k < K; k += 4) {
        float4 w0 = sW4[(k + 0) * 16 + fq];
        float4 w1 = sW4[(k + 1) * 16 + fq];
        float4 w2 = sW4[(k + 2) * 16 + fq];
        float4 w3 = sW4[(k + 3) * 16 + fq];
#pragma unroll
        for (int i = 0; i < 4; ++i) {
            float4 xv = *(const float4*)&xs[(r0 + i) * XSTR + k];
            acc[i].x = fmaf(xv.x, w0.x, acc[i].x);
            acc[i].y = fmaf(xv.x, w0.y, acc[i].y);
            acc[i].z = fmaf(xv.x, w0.z, acc[i].z);
            acc[i].w = fmaf(xv.x, w0.w, acc[i].w);
            acc[i].x = fmaf(xv.y, w1.x, acc[i].x);
            acc[i].y = fmaf(xv.y, w1.y, acc[i].y);
            acc[i].z = fmaf(xv.y, w1.z, acc[i].z);
            acc[i].w = fmaf(xv.y, w1.w, acc[i].w);
            acc[i].x = fmaf(xv.z, w2.x, acc[i].x);
            acc[i].y = fmaf(xv.z, w2.y, acc[i].y);
            acc[i].z = fmaf(xv.z, w2.z, acc[i].z);
            acc[i].w = fmaf(xv.z, w2.w, acc[i].w);
            acc[i].x = fmaf(xv.w, w3.x, acc[i].x);
            acc[i].y = fmaf(xv.w, w3.y, acc[i].y);
            acc[i].z = fmaf(xv.w, w3.z, acc[i].z);
            acc[i].w = fmaf(xv.w, w3.w, acc[i].w);
        }
    }

#pragma unroll
    for (int i = 0; i < 4; ++i) {
        int rg = base + r0 + i;
        if (rg < n) {
            ushort4 us;
            us.x = f2bf(acc[i].x); us.y = f2bf(acc[i].y);
            us.z = f2bf(acc[i].z); us.w = f2bf(acc[i].w);
            *(ushort4*)(outbf + (size_t)rg * FOUT + fq * 4) = us;
        }
    }
}

// ---------------- bucket binning ----------------
__global__ __launch_bounds__(512) void k_init(int* __restrict__ gcursor) {
    gcursor[threadIdx.x] = threadIdx.x * CAP;
}

__global__ __launch_bounds__(256) void k_bin(
    const int* __restrict__ src, const int* __restrict__ dst,
    int* __restrict__ gcursor, int* __restrict__ bins, int ne) {
    __shared__ int cnt[NBUCKET];
    __shared__ int gbase[NBUCKET];

    const int t = threadIdx.x;
    const int cbeg = blockIdx.x * CHUNK;
    const int cend = min(cbeg + CHUNK, ne);

    for (int i = t; i < NBUCKET; i += 256) cnt[i] = 0;
    __syncthreads();

    for (int e = cbeg + t; e < cend; e += 256)
        atomicAdd(&cnt[dst[e] / NPB2], 1);
    __syncthreads();

    for (int i = t; i < NBUCKET; i += 256) {
        int c = cnt[i];
        gbase[i] = (c > 0) ? atomicAdd(&gcursor[i], c) : 0;
    }
    __syncthreads();
    for (int i = t; i < NBUCKET; i += 256) cnt[i] = 0;   // reuse as local cursor
    __syncthreads();

    for (int e = cbeg + t; e < cend; e += 256) {
        int d = dst[e];
        int b = d / NPB2;
        int dl = d - b * NPB2;
        int lpos = atomicAdd(&cnt[b], 1);
        int gpos = gbase[b] + lpos;
        if (gpos < (b + 1) * CAP)          // capacity guard (never hit here)
            bins[gpos] = src[e] | (dl << 17);
    }
}

__global__ __launch_bounds__(512) void k_bscan(
    const int* __restrict__ gcursor, int* __restrict__ bucket_base) {
    __shared__ int s[512];
    const int t = threadIdx.x;
    int c = 0;
    if (t < NBUCKET) c = min(gcursor[t] - t * CAP, CAP);
    s[t] = c;
    __syncthreads();
    for (int ofs = 1; ofs < 512; ofs <<= 1) {
        int v = (t >= ofs) ? s[t - ofs] : 0;
        __syncthreads();
        s[t] += v;
        __syncthreads();
    }
    if (t < NBUCKET) bucket_base[t] = s[t] - c;
}

// Per-bucket LDS sort into per-node CSR (dense contiguous writes).
__global__ __launch_bounds__(256) void k_csr(
    const int* __restrict__ gcursor, const int* __restrict__ bins,
    const int* __restrict__ bucket_base, int* __restrict__ row_ofs,
    int* __restrict__ csr_src, int n) {
    __shared__ int recs[CAP];
    __shared__ int cnt[NPB2];
    __shared__ int cur[NPB2];
    __shared__ int sscan[256];

    const int t = threadIdx.x;
    const int b = blockIdx.x;
    const int c = min(gcursor[b] - b * CAP, CAP);
    const int baseg = bucket_base[b];

    for (int i = t; i < c; i += 256) recs[i] = bins[b * CAP + i];
    for (int i = t; i < NPB2; i += 256) cnt[i] = 0;
    __syncthreads();

    for (int i = t; i < c; i += 256)
        atomicAdd(&cnt[((unsigned)recs[i]) >> 17], 1);
    __syncthreads();

    int v = (t < NPB2) ? cnt[t] : 0;
    sscan[t] = v;
    __syncthreads();
    for (int o = 1; o < 256; o <<= 1) {
        int u = (t >= o) ? sscan[t - o] : 0;
        __syncthreads();
        sscan[t] += u;
        __syncthreads();
    }
    if (t < NPB2) {
        cur[t] = sscan[t] - v;
        int node = b * NPB2 + t;
        if (node <= n) row_ofs[node] = baseg + sscan[t] - v;
    }
    __syncthreads();

    for (int i = t; i < c; i += 256) {
        unsigned r = (unsigned)recs[i];
        int dl = r >> 17;
        int p = atomicAdd(&cur[dl], 1);
        csr_src[baseg + p] = (int)(r & 0x1FFFF);
    }
}

// ---------------- aggregation (2 edges per load) ----------------
// One wave per node. lane = (half = edge parity, p = feature pair).
// Each uint load covers 2 bf16 features of one edge; a wave instruction
// covers 2 full edges. shfl_xor(32) combines halves. 4 groups in flight.
// ACT: 0 = ReLU, 1 = sigmoid. OUTBF: bf16 (1) or f32 (0) output.
template<int ACT, int OUTBF>
__global__ __launch_bounds__(256) void k_agg(
    const int* __restrict__ row_ofs, const int* __restrict__ csr_src,
    const unsigned* __restrict__ msg32, const float* __restrict__ bias,
    void* __restrict__ outv, int n) {
    const int node = blockIdx.x * 4 + (threadIdx.x >> 6);
    if (node >= n) return;
    const int lane = threadIdx.x & 63;
    const int half = lane >> 5;        // which edge of the pair
    const int p = lane & 31;           // feature pair (2p, 2p+1)
    const int beg = row_ofs[node];
    const int end = row_ofs[node + 1];

    float a0 = 0.f, a1 = 0.f;
    int j = beg;
    for (; j + 8 <= end; j += 8) {
        int sA = csr_src[j + 0 + half];
        int sB = csr_src[j + 2 + half];
        int sC = csr_src[j + 4 + half];
        int sD = csr_src[j + 6 + half];
        unsigned vA = msg32[(size_t)sA * 32 + p];
        unsigned vB = msg32[(size_t)sB * 32 + p];
        unsigned vC = msg32[(size_t)sC * 32 + p];
        unsigned vD = msg32[(size_t)sD * 32 + p];
        a0 += bflo(vA) + bflo(vB) + bflo(vC) + bflo(vD);
        a1 += bfhi(vA) + bfhi(vB) + bfhi(vC) + bfhi(vD);
    }
    for (; j < end; j += 2) {
        if (j + half < end) {
            int s = csr_src[j + half];
            unsigned v = msg32[(size_t)s * 32 + p];
            a0 += bflo(v);
            a1 += bfhi(v);
        }
    }
    a0 += __shfl_xor(a0, 32);
    a1 += __shfl_xor(a1, 32);

    if (half == 0) {
        float v0 = a0 + bias[2 * p];
        float v1 = a1 + bias[2 * p + 1];
        if (ACT == 0) {
            v0 = fmaxf(v0, 0.f);
            v1 = fmaxf(v1, 0.f);
        } else {
            v0 = 1.f / (1.f + __expf(-v0));
            v1 = 1.f / (1.f + __expf(-v1));
        }
        if (OUTBF) {
            ushort2 us; us.x = f2bf(v0); us.y = f2bf(v1);
            *(ushort2*)((unsigned short*)outv + (size_t)node * FOUT + 2 * p) = us;
        } else {
            float2 f2; f2.x = v0; f2.y = v1;
            *(float2*)((float*)outv + (size_t)node * FOUT + 2 * p) = f2;
        }
    }
}

extern "C" void kernel_launch(void* const* d_in, const int* in_sizes, int n_in,
                              void* d_out, int out_size, void* d_ws, size_t ws_size,
                              hipStream_t stream) {
    const float* x  = (const float*)d_in[0];
    const int*   ei = (const int*)d_in[1];
    const float* W1 = (const float*)d_in[2];
    const float* b1 = (const float*)d_in[3];
    const float* W2 = (const float*)d_in[4];
    const float* b2 = (const float*)d_in[5];
    const float* W3 = (const float*)d_in[6];
    const float* b3 = (const float*)d_in[7];
    float* out = (float*)d_out;

    const int n  = in_sizes[0] / 128;   // 100000
    const int ne = in_sizes[1] / 2;     // 1600000
    const int* src = ei;
    const int* dst = ei + ne;

    const size_t feat_elems = (size_t)n * FOUT;

    // workspace layout
    unsigned short* msg16 = (unsigned short*)d_ws;              // 12.8MB bf16
    unsigned short* B16   = msg16 + feat_elems;                 // 12.8MB bf16
    int*   bins     = (int*)(B16 + feat_elems);                 // 8.4MB
    int*   gcursor  = bins + (size_t)NBUCKET * CAP;             // 511
    int*   bucket_base = gcursor + 512;                         // 512
    int*   row_ofs  = bucket_base + 512;                        // n+1
    int*   csr_src  = row_ofs + n + 1;                          // ne

    const int gLin = (n + 63) / 64;
    const int gBin = (ne + CHUNK - 1) / CHUNK;   // 196
    const int gAgg = (n + 3) / 4;                // 25000

    // ---- CSR build (every call: ws is re-poisoned) ----
    k_init<<<1, NBUCKET, 0, stream>>>(gcursor);
    k_bin<<<gBin, 256, 0, stream>>>(src, dst, gcursor, bins, ne);
    k_bscan<<<1, 512, 0, stream>>>(gcursor, bucket_base);
    k_csr<<<NBUCKET, 256, 0, stream>>>(gcursor, bins, bucket_base, row_ofs, csr_src, n);

    // ---- Layer 1 ----
    k_linear<128, 0><<<gLin, 256, 0, stream>>>(x, W1, msg16, n);
    k_agg<0, 1><<<gAgg, 256, 0, stream>>>(row_ofs, csr_src, (const unsigned*)msg16, b1, B16, n);
    // ---- Layer 2 ----
    k_linear<64, 1><<<gLin, 256, 0, stream>>>(B16, W2, msg16, n);
    k_agg<0, 1><<<gAgg, 256, 0, stream>>>(row_ofs, csr_src, (const unsigned*)msg16, b2, B16, n);
    // ---- Layer 3 ----
    k_linear<64, 1><<<gLin, 256, 0, stream>>>(B16, W3, msg16, n);
    k_agg<1, 0><<<gAgg, 256, 0, stream>>>(row_ofs, csr_src, (const unsigned*)msg16, b3, out, n);
}

// Round 11
// 356.745 us; speedup vs baseline: 5.0144x; 1.0551x over previous
//
#include <hip/hip_runtime.h>

// GCN: 3x (linear(bf16 msg) -> per-node CSR gather-reduce -> bias+act).
// N=100000, E=1600000, IN=128, HID=OUT=64.
// R11: k_agg gathers 8 edges per uint4 load (lane = e8|fo), shfl_xor(8/16/32)
//      edge-slot reduce; 0.25 vmem instructions per edge.

#define FOUT 64
#define NPB2 196          // dst nodes per bucket
#define NBUCKET 511       // ceil(100000/196)
#define CAP 4096          // records per bucket (mean 3131)
#define CHUNK 8192        // edges per bin-block

// ---------------- helpers ----------------
__device__ __forceinline__ unsigned short f2bf(float f) {
    unsigned u = __float_as_uint(f);
    u += 0x7FFF + ((u >> 16) & 1);          // round-to-nearest-even
    return (unsigned short)(u >> 16);
}
__device__ __forceinline__ float bflo(unsigned u) {   // low bf16 of a uint
    return __uint_as_float(u << 16);
}
__device__ __forceinline__ float bfhi(unsigned u) {   // high bf16 of a uint
    return __uint_as_float(u & 0xFFFF0000u);
}
__device__ __forceinline__ unsigned pack2(float lo, float hi) {
    return (unsigned)f2bf(lo) | ((unsigned)f2bf(hi) << 16);
}

// ---------------- dense linear (f32|bf16 in, bf16 out) ----------------
// Register-tiled: 256 thr = 4 waves, 64 rows/block, full K staged in LDS.
// Thread owns 4 features x 4 rows; W and x both read as ds_read_b128.
template<int K, int INBF>
__global__ __launch_bounds__(256) void k_linear(
    const void* __restrict__ inv, const float* __restrict__ W,
    unsigned short* __restrict__ outbf, int n) {
    constexpr int XSTR = (K == 128) ? 132 : 68;
    __shared__ float4 sW4[K * 16];
    __shared__ float xs[64 * XSTR];

    const int t = threadIdx.x;
    const int base = blockIdx.x * 64;

    const float4* W4 = (const float4*)W;
#pragma unroll
    for (int i = 0; i < K * 16 / 256; ++i) sW4[t + i * 256] = W4[t + i * 256];

    if (INBF) {
        const unsigned short* in16 = (const unsigned short*)inv;
        constexpr int QPR = K / 8;                    // uint4 per row
#pragma unroll
        for (int i = 0; i < 64 * QPR / 256; ++i) {
            int flat = t + i * 256;
            int row = flat / QPR;
            int q = flat % QPR;
            int rg = base + row;
            if (rg < n) {
                uint4 u = *(const uint4*)(in16 + (size_t)rg * K + q * 8);
                float* xp = &xs[row * XSTR + q * 8];
                float4 a, b;
                a.x = bflo(u.x); a.y = bfhi(u.x);
                a.z = bflo(u.y); a.w = bfhi(u.y);
                b.x = bflo(u.z); b.y = bfhi(u.z);
                b.z = bflo(u.w); b.w = bfhi(u.w);
                *(float4*)(xp) = a;
                *(float4*)(xp + 4) = b;
            }
        }
    } else {
        const float* in = (const float*)inv;
        constexpr int CPR = K / 4;                    // float4 per row
#pragma unroll
        for (int i = 0; i < 64 * CPR / 256; ++i) {
            int flat = t + i * 256;
            int row = flat / CPR;
            int c4 = flat % CPR;
            int rg = base + row;
            if (rg < n) {
                float4 v = *(const float4*)(in + (size_t)rg * K + c4 * 4);
                *(float4*)&xs[row * XSTR + c4 * 4] = v;
            }
        }
    }
    __syncthreads();

    const int fq = t & 15;
    const int slot = (t >> 4) & 3;
    const int wave = t >> 6;
    const int r0 = wave * 16 + slot * 4;

    float4 acc[4];
#pragma unroll
    for (int i = 0; i < 4; ++i) acc[i] = make_float4(0.f, 0.f, 0.f, 0.f);

#pragma unroll 8
    for (int k = 0; k < K; k += 4) {
        float4 w0 = sW4[(k + 0) * 16 + fq];
        float4 w1 = sW4[(k + 1) * 16 + fq];
        float4 w2 = sW4[(k + 2) * 16 + fq];
        float4 w3 = sW4[(k + 3) * 16 + fq];
#pragma unroll
        for (int i = 0; i < 4; ++i) {
            float4 xv = *(const float4*)&xs[(r0 + i) * XSTR + k];
            acc[i].x = fmaf(xv.x, w0.x, acc[i].x);
            acc[i].y = fmaf(xv.x, w0.y, acc[i].y);
            acc[i].z = fmaf(xv.x, w0.z, acc[i].z);
            acc[i].w = fmaf(xv.x, w0.w, acc[i].w);
            acc[i].x = fmaf(xv.y, w1.x, acc[i].x);
            acc[i].y = fmaf(xv.y, w1.y, acc[i].y);
            acc[i].z = fmaf(xv.y, w1.z, acc[i].z);
            acc[i].w = fmaf(xv.y, w1.w, acc[i].w);
            acc[i].x = fmaf(xv.z, w2.x, acc[i].x);
            acc[i].y = fmaf(xv.z, w2.y, acc[i].y);
            acc[i].z = fmaf(xv.z, w2.z, acc[i].z);
            acc[i].w = fmaf(xv.z, w2.w, acc[i].w);
            acc[i].x = fmaf(xv.w, w3.x, acc[i].x);
            acc[i].y = fmaf(xv.w, w3.y, acc[i].y);
            acc[i].z = fmaf(xv.w, w3.z, acc[i].z);
            acc[i].w = fmaf(xv.w, w3.w, acc[i].w);
        }
    }

#pragma unroll
    for (int i = 0; i < 4; ++i) {
        int rg = base + r0 + i;
        if (rg < n) {
            ushort4 us;
            us.x = f2bf(acc[i].x); us.y = f2bf(acc[i].y);
            us.z = f2bf(acc[i].z); us.w = f2bf(acc[i].w);
            *(ushort4*)(outbf + (size_t)rg * FOUT + fq * 4) = us;
        }
    }
}

// ---------------- bucket binning ----------------
__global__ __launch_bounds__(512) void k_init(int* __restrict__ gcursor) {
    gcursor[threadIdx.x] = threadIdx.x * CAP;
}

__global__ __launch_bounds__(256) void k_bin(
    const int* __restrict__ src, const int* __restrict__ dst,
    int* __restrict__ gcursor, int* __restrict__ bins, int ne) {
    __shared__ int cnt[NBUCKET];
    __shared__ int gbase[NBUCKET];

    const int t = threadIdx.x;
    const int cbeg = blockIdx.x * CHUNK;
    const int cend = min(cbeg + CHUNK, ne);

    for (int i = t; i < NBUCKET; i += 256) cnt[i] = 0;
    __syncthreads();

    for (int e = cbeg + t; e < cend; e += 256)
        atomicAdd(&cnt[dst[e] / NPB2], 1);
    __syncthreads();

    for (int i = t; i < NBUCKET; i += 256) {
        int c = cnt[i];
        gbase[i] = (c > 0) ? atomicAdd(&gcursor[i], c) : 0;
    }
    __syncthreads();
    for (int i = t; i < NBUCKET; i += 256) cnt[i] = 0;   // reuse as local cursor
    __syncthreads();

    for (int e = cbeg + t; e < cend; e += 256) {
        int d = dst[e];
        int b = d / NPB2;
        int dl = d - b * NPB2;
        int lpos = atomicAdd(&cnt[b], 1);
        int gpos = gbase[b] + lpos;
        if (gpos < (b + 1) * CAP)          // capacity guard (never hit here)
            bins[gpos] = src[e] | (dl << 17);
    }
}

__global__ __launch_bounds__(512) void k_bscan(
    const int* __restrict__ gcursor, int* __restrict__ bucket_base) {
    __shared__ int s[512];
    const int t = threadIdx.x;
    int c = 0;
    if (t < NBUCKET) c = min(gcursor[t] - t * CAP, CAP);
    s[t] = c;
    __syncthreads();
    for (int ofs = 1; ofs < 512; ofs <<= 1) {
        int v = (t >= ofs) ? s[t - ofs] : 0;
        __syncthreads();
        s[t] += v;
        __syncthreads();
    }
    if (t < NBUCKET) bucket_base[t] = s[t] - c;
}

// Per-bucket LDS sort into per-node CSR (dense contiguous writes).
__global__ __launch_bounds__(256) void k_csr(
    const int* __restrict__ gcursor, const int* __restrict__ bins,
    const int* __restrict__ bucket_base, int* __restrict__ row_ofs,
    int* __restrict__ csr_src, int n) {
    __shared__ int recs[CAP];
    __shared__ int cnt[NPB2];
    __shared__ int cur[NPB2];
    __shared__ int sscan[256];

    const int t = threadIdx.x;
    const int b = blockIdx.x;
    const int c = min(gcursor[b] - b * CAP, CAP);
    const int baseg = bucket_base[b];

    for (int i = t; i < c; i += 256) recs[i] = bins[b * CAP + i];
    for (int i = t; i < NPB2; i += 256) cnt[i] = 0;
    __syncthreads();

    for (int i = t; i < c; i += 256)
        atomicAdd(&cnt[((unsigned)recs[i]) >> 17], 1);
    __syncthreads();

    int v = (t < NPB2) ? cnt[t] : 0;
    sscan[t] = v;
    __syncthreads();
    for (int o = 1; o < 256; o <<= 1) {
        int u = (t >= o) ? sscan[t - o] : 0;
        __syncthreads();
        sscan[t] += u;
        __syncthreads();
    }
    if (t < NPB2) {
        cur[t] = sscan[t] - v;
        int node = b * NPB2 + t;
        if (node <= n) row_ofs[node] = baseg + sscan[t] - v;
    }
    __syncthreads();

    for (int i = t; i < c; i += 256) {
        unsigned r = (unsigned)recs[i];
        int dl = r >> 17;
        int p = atomicAdd(&cur[dl], 1);
        csr_src[baseg + p] = (int)(r & 0x1FFFF);
    }
}

// ---------------- aggregation (8 edges per uint4 gather) ----------------
// One wave per node. lane = (e8 = edge slot, fo = feature octet).
// One uint4 gather instruction covers 8 full bf16 rows; per 8-edge step:
// 1 coalesced index load + 1 gather. shfl_xor(8/16/32) edge-slot reduce.
// ACT: 0 = ReLU, 1 = sigmoid. OUTBF: bf16 (1) or f32 (0) output.
template<int ACT, int OUTBF>
__global__ __launch_bounds__(256) void k_agg(
    const int* __restrict__ row_ofs, const int* __restrict__ csr_src,
    const uint4* __restrict__ msg4, const float* __restrict__ bias,
    void* __restrict__ outv, int n) {
    const int node = blockIdx.x * 4 + (threadIdx.x >> 6);
    if (node >= n) return;
    const int lane = threadIdx.x & 63;
    const int e8 = lane >> 3;          // edge slot within the 8-edge step
    const int fo = lane & 7;           // feature octet (uint4 index in row)
    const int beg = row_ofs[node];
    const int end = row_ofs[node + 1];

    float a0 = 0.f, a1 = 0.f, a2 = 0.f, a3 = 0.f;
    float a4 = 0.f, a5 = 0.f, a6 = 0.f, a7 = 0.f;

    for (int j = beg + e8; j < end; j += 8) {
        int s = csr_src[j];
        uint4 v = msg4[(size_t)s * 8 + fo];
        a0 += bflo(v.x); a1 += bfhi(v.x);
        a2 += bflo(v.y); a3 += bfhi(v.y);
        a4 += bflo(v.z); a5 += bfhi(v.z);
        a6 += bflo(v.w); a7 += bfhi(v.w);
    }

#pragma unroll
    for (int m = 8; m < 64; m <<= 1) {
        a0 += __shfl_xor(a0, m); a1 += __shfl_xor(a1, m);
        a2 += __shfl_xor(a2, m); a3 += __shfl_xor(a3, m);
        a4 += __shfl_xor(a4, m); a5 += __shfl_xor(a5, m);
        a6 += __shfl_xor(a6, m); a7 += __shfl_xor(a7, m);
    }

    if (e8 == 0) {
        const float4 b0 = *(const float4*)(bias + fo * 8);
        const float4 b1 = *(const float4*)(bias + fo * 8 + 4);
        float v0 = a0 + b0.x, v1 = a1 + b0.y, v2 = a2 + b0.z, v3 = a3 + b0.w;
        float v4 = a4 + b1.x, v5 = a5 + b1.y, v6 = a6 + b1.z, v7 = a7 + b1.w;
        if (ACT == 0) {
            v0 = fmaxf(v0, 0.f); v1 = fmaxf(v1, 0.f);
            v2 = fmaxf(v2, 0.f); v3 = fmaxf(v3, 0.f);
            v4 = fmaxf(v4, 0.f); v5 = fmaxf(v5, 0.f);
            v6 = fmaxf(v6, 0.f); v7 = fmaxf(v7, 0.f);
        } else {
            v0 = 1.f / (1.f + __expf(-v0)); v1 = 1.f / (1.f + __expf(-v1));
            v2 = 1.f / (1.f + __expf(-v2)); v3 = 1.f / (1.f + __expf(-v3));
            v4 = 1.f / (1.f + __expf(-v4)); v5 = 1.f / (1.f + __expf(-v5));
            v6 = 1.f / (1.f + __expf(-v6)); v7 = 1.f / (1.f + __expf(-v7));
        }
        if (OUTBF) {
            uint4 u;
            u.x = pack2(v0, v1); u.y = pack2(v2, v3);
            u.z = pack2(v4, v5); u.w = pack2(v6, v7);
            *(uint4*)((unsigned short*)outv + (size_t)node * FOUT + fo * 8) = u;
        } else {
            float* op = (float*)outv + (size_t)node * FOUT + fo * 8;
            *(float4*)op = make_float4(v0, v1, v2, v3);
            *(float4*)(op + 4) = make_float4(v4, v5, v6, v7);
        }
    }
}

extern "C" void kernel_launch(void* const* d_in, const int* in_sizes, int n_in,
                              void* d_out, int out_size, void* d_ws, size_t ws_size,
                              hipStream_t stream) {
    const float* x  = (const float*)d_in[0];
    const int*   ei = (const int*)d_in[1];
    const float* W1 = (const float*)d_in[2];
    const float* b1 = (const float*)d_in[3];
    const float* W2 = (const float*)d_in[4];
    const float* b2 = (const float*)d_in[5];
    const float* W3 = (const float*)d_in[6];
    const float* b3 = (const float*)d_in[7];
    float* out = (float*)d_out;

    const int n  = in_sizes[0] / 128;   // 100000
    const int ne = in_sizes[1] / 2;     // 1600000
    const int* src = ei;
    const int* dst = ei + ne;

    const size_t feat_elems = (size_t)n * FOUT;

    // workspace layout
    unsigned short* msg16 = (unsigned short*)d_ws;              // 12.8MB bf16
    unsigned short* B16   = msg16 + feat_elems;                 // 12.8MB bf16
    int*   bins     = (int*)(B16 + feat_elems);                 // 8.4MB
    int*   gcursor  = bins + (size_t)NBUCKET * CAP;             // 511
    int*   bucket_base = gcursor + 512;                         // 512
    int*   row_ofs  = bucket_base + 512;                        // n+1
    int*   csr_src  = row_ofs + n + 1;                          // ne

    const int gLin = (n + 63) / 64;
    const int gBin = (ne + CHUNK - 1) / CHUNK;   // 196
    const int gAgg = (n + 3) / 4;                // 25000

    // ---- CSR build (every call: ws is re-poisoned) ----
    k_init<<<1, NBUCKET, 0, stream>>>(gcursor);
    k_bin<<<gBin, 256, 0, stream>>>(src, dst, gcursor, bins, ne);
    k_bscan<<<1, 512, 0, stream>>>(gcursor, bucket_base);
    k_csr<<<NBUCKET, 256, 0, stream>>>(gcursor, bins, bucket_base, row_ofs, csr_src, n);

    // ---- Layer 1 ----
    k_linear<128, 0><<<gLin, 256, 0, stream>>>(x, W1, msg16, n);
    k_agg<0, 1><<<gAgg, 256, 0, stream>>>(row_ofs, csr_src, (const uint4*)msg16, b1, B16, n);
    // ---- Layer 2 ----
    k_linear<64, 1><<<gLin, 256, 0, stream>>>(B16, W2, msg16, n);
    k_agg<0, 1><<<gAgg, 256, 0, stream>>>(row_ofs, csr_src, (const uint4*)msg16, b2, B16, n);
    // ---- Layer 3 ----
    k_linear<64, 1><<<gLin, 256, 0, stream>>>(B16, W3, msg16, n);
    k_agg<1, 0><<<gAgg, 256, 0, stream>>>(row_ofs, csr_src, (const uint4*)msg16, b3, out, n);
}

// Round 12
// 330.073 us; speedup vs baseline: 5.4196x; 1.0808x over previous
//
#include <hip/hip_runtime.h>

// GCN: 3x (linear(bf16 msg) -> per-node CSR gather-reduce -> bias+act).
// N=100000, E=1600000, IN=128, HID=OUT=64.
// R12: k_agg 4 nodes/wave (lane = nsub|e2|fo) -> reduce tail 24->2 shfl/node;
//      k_bscan folded into k_csr (self-computed prefix base).

#define FOUT 64
#define NPB2 196          // dst nodes per bucket
#define NBUCKET 511       // ceil(100000/196)
#define CAP 4096          // records per bucket (mean 3131)
#define CHUNK 8192        // edges per bin-block

// ---------------- helpers ----------------
__device__ __forceinline__ unsigned short f2bf(float f) {
    unsigned u = __float_as_uint(f);
    u += 0x7FFF + ((u >> 16) & 1);          // round-to-nearest-even
    return (unsigned short)(u >> 16);
}
__device__ __forceinline__ float bflo(unsigned u) {   // low bf16 of a uint
    return __uint_as_float(u << 16);
}
__device__ __forceinline__ float bfhi(unsigned u) {   // high bf16 of a uint
    return __uint_as_float(u & 0xFFFF0000u);
}
__device__ __forceinline__ unsigned pack2(float lo, float hi) {
    return (unsigned)f2bf(lo) | ((unsigned)f2bf(hi) << 16);
}

// ---------------- dense linear (f32|bf16 in, bf16 out) ----------------
// Register-tiled: 256 thr = 4 waves, 64 rows/block, full K staged in LDS.
// Thread owns 4 features x 4 rows; W and x both read as ds_read_b128.
template<int K, int INBF>
__global__ __launch_bounds__(256) void k_linear(
    const void* __restrict__ inv, const float* __restrict__ W,
    unsigned short* __restrict__ outbf, int n) {
    constexpr int XSTR = (K == 128) ? 132 : 68;
    __shared__ float4 sW4[K * 16];
    __shared__ float xs[64 * XSTR];

    const int t = threadIdx.x;
    const int base = blockIdx.x * 64;

    const float4* W4 = (const float4*)W;
#pragma unroll
    for (int i = 0; i < K * 16 / 256; ++i) sW4[t + i * 256] = W4[t + i * 256];

    if (INBF) {
        const unsigned short* in16 = (const unsigned short*)inv;
        constexpr int QPR = K / 8;                    // uint4 per row
#pragma unroll
        for (int i = 0; i < 64 * QPR / 256; ++i) {
            int flat = t + i * 256;
            int row = flat / QPR;
            int q = flat % QPR;
            int rg = base + row;
            if (rg < n) {
                uint4 u = *(const uint4*)(in16 + (size_t)rg * K + q * 8);
                float* xp = &xs[row * XSTR + q * 8];
                float4 a, b;
                a.x = bflo(u.x); a.y = bfhi(u.x);
                a.z = bflo(u.y); a.w = bfhi(u.y);
                b.x = bflo(u.z); b.y = bfhi(u.z);
                b.z = bflo(u.w); b.w = bfhi(u.w);
                *(float4*)(xp) = a;
                *(float4*)(xp + 4) = b;
            }
        }
    } else {
        const float* in = (const float*)inv;
        constexpr int CPR = K / 4;                    // float4 per row
#pragma unroll
        for (int i = 0; i < 64 * CPR / 256; ++i) {
            int flat = t + i * 256;
            int row = flat / CPR;
            int c4 = flat % CPR;
            int rg = base + row;
            if (rg < n) {
                float4 v = *(const float4*)(in + (size_t)rg * K + c4 * 4);
                *(float4*)&xs[row * XSTR + c4 * 4] = v;
            }
        }
    }
    __syncthreads();

    const int fq = t & 15;
    const int slot = (t >> 4) & 3;
    const int wave = t >> 6;
    const int r0 = wave * 16 + slot * 4;

    float4 acc[4];
#pragma unroll
    for (int i = 0; i < 4; ++i) acc[i] = make_float4(0.f, 0.f, 0.f, 0.f);

#pragma unroll 8
    for (int k = 0; k < K; k += 4) {
        float4 w0 = sW4[(k + 0) * 16 + fq];
        float4 w1 = sW4[(k + 1) * 16 + fq];
        float4 w2 = sW4[(k + 2) * 16 + fq];
        float4 w3 = sW4[(k + 3) * 16 + fq];
#pragma unroll
        for (int i = 0; i < 4; ++i) {
            float4 xv = *(const float4*)&xs[(r0 + i) * XSTR + k];
            acc[i].x = fmaf(xv.x, w0.x, acc[i].x);
            acc[i].y = fmaf(xv.x, w0.y, acc[i].y);
            acc[i].z = fmaf(xv.x, w0.z, acc[i].z);
            acc[i].w = fmaf(xv.x, w0.w, acc[i].w);
            acc[i].x = fmaf(xv.y, w1.x, acc[i].x);
            acc[i].y = fmaf(xv.y, w1.y, acc[i].y);
            acc[i].z = fmaf(xv.y, w1.z, acc[i].z);
            acc[i].w = fmaf(xv.y, w1.w, acc[i].w);
            acc[i].x = fmaf(xv.z, w2.x, acc[i].x);
            acc[i].y = fmaf(xv.z, w2.y, acc[i].y);
            acc[i].z = fmaf(xv.z, w2.z, acc[i].z);
            acc[i].w = fmaf(xv.z, w2.w, acc[i].w);
            acc[i].x = fmaf(xv.w, w3.x, acc[i].x);
            acc[i].y = fmaf(xv.w, w3.y, acc[i].y);
            acc[i].z = fmaf(xv.w, w3.z, acc[i].z);
            acc[i].w = fmaf(xv.w, w3.w, acc[i].w);
        }
    }

#pragma unroll
    for (int i = 0; i < 4; ++i) {
        int rg = base + r0 + i;
        if (rg < n) {
            ushort4 us;
            us.x = f2bf(acc[i].x); us.y = f2bf(acc[i].y);
            us.z = f2bf(acc[i].z); us.w = f2bf(acc[i].w);
            *(ushort4*)(outbf + (size_t)rg * FOUT + fq * 4) = us;
        }
    }
}

// ---------------- bucket binning ----------------
__global__ __launch_bounds__(512) void k_init(int* __restrict__ gcursor) {
    gcursor[threadIdx.x] = threadIdx.x * CAP;
}

__global__ __launch_bounds__(256) void k_bin(
    const int* __restrict__ src, const int* __restrict__ dst,
    int* __restrict__ gcursor, int* __restrict__ bins, int ne) {
    __shared__ int cnt[NBUCKET];
    __shared__ int gbase[NBUCKET];

    const int t = threadIdx.x;
    const int cbeg = blockIdx.x * CHUNK;
    const int cend = min(cbeg + CHUNK, ne);

    for (int i = t; i < NBUCKET; i += 256) cnt[i] = 0;
    __syncthreads();

    for (int e = cbeg + t; e < cend; e += 256)
        atomicAdd(&cnt[dst[e] / NPB2], 1);
    __syncthreads();

    for (int i = t; i < NBUCKET; i += 256) {
        int c = cnt[i];
        gbase[i] = (c > 0) ? atomicAdd(&gcursor[i], c) : 0;
    }
    __syncthreads();
    for (int i = t; i < NBUCKET; i += 256) cnt[i] = 0;   // reuse as local cursor
    __syncthreads();

    for (int e = cbeg + t; e < cend; e += 256) {
        int d = dst[e];
        int b = d / NPB2;
        int dl = d - b * NPB2;
        int lpos = atomicAdd(&cnt[b], 1);
        int gpos = gbase[b] + lpos;
        if (gpos < (b + 1) * CAP)          // capacity guard (never hit here)
            bins[gpos] = src[e] | (dl << 17);
    }
}

// Per-bucket LDS sort into per-node CSR (dense contiguous writes).
// Each block self-computes its global base (partial sum over bucket counts),
// replacing the separate k_bscan launch.
__global__ __launch_bounds__(256) void k_csr(
    const int* __restrict__ gcursor, const int* __restrict__ bins,
    int* __restrict__ row_ofs, int* __restrict__ csr_src, int n) {
    __shared__ int recs[CAP];
    __shared__ int cnt[NPB2];
    __shared__ int cur[NPB2];
    __shared__ int sscan[256];
    __shared__ int spart[256];

    const int t = threadIdx.x;
    const int b = blockIdx.x;
    const int c = min(gcursor[b] - b * CAP, CAP);

    // self-computed prefix base: sum of counts of buckets < b
    int part = 0;
    for (int i = t; i < b; i += 256)
        part += min(gcursor[i] - i * CAP, CAP);
    spart[t] = part;
    __syncthreads();
    for (int o = 128; o > 0; o >>= 1) {
        if (t < o) spart[t] += spart[t + o];
        __syncthreads();
    }
    const int baseg = spart[0];
    __syncthreads();

    for (int i = t; i < c; i += 256) recs[i] = bins[b * CAP + i];
    for (int i = t; i < NPB2; i += 256) cnt[i] = 0;
    __syncthreads();

    for (int i = t; i < c; i += 256)
        atomicAdd(&cnt[((unsigned)recs[i]) >> 17], 1);
    __syncthreads();

    int v = (t < NPB2) ? cnt[t] : 0;
    sscan[t] = v;
    __syncthreads();
    for (int o = 1; o < 256; o <<= 1) {
        int u = (t >= o) ? sscan[t - o] : 0;
        __syncthreads();
        sscan[t] += u;
        __syncthreads();
    }
    if (t < NPB2) {
        cur[t] = sscan[t] - v;
        int node = b * NPB2 + t;
        if (node <= n) row_ofs[node] = baseg + sscan[t] - v;
    }
    __syncthreads();

    for (int i = t; i < c; i += 256) {
        unsigned r = (unsigned)recs[i];
        int dl = r >> 17;
        int p = atomicAdd(&cur[dl], 1);
        csr_src[baseg + p] = (int)(r & 0x1FFFF);
    }
}

// ---------------- aggregation (4 nodes/wave, 8 edges per uint4 gather) ----
// lane = nsub[2] | e2[1] | fo[3]: 4 nodes per wave, 2 edge slots per node,
// 8 feature octets. One uint4 gather instr covers 8 full bf16 rows (8 edges
// across 4 nodes). Cross-lane reduce = ONE shfl_xor(8) round (2 shfl/node
// vs 24 in the 1-node/wave layout). ACT: 0 = ReLU, 1 = sigmoid.
template<int ACT, int OUTBF>
__global__ __launch_bounds__(256) void k_agg(
    const int* __restrict__ row_ofs, const int* __restrict__ csr_src,
    const uint4* __restrict__ msg4, const float* __restrict__ bias,
    void* __restrict__ outv, int n) {
    const int wave = threadIdx.x >> 6;
    const int lane = threadIdx.x & 63;
    const int nsub = lane >> 4;        // node within wave (0..3)
    const int e2 = (lane >> 3) & 1;    // edge slot
    const int fo = lane & 7;           // feature octet
    const int node = (blockIdx.x * 4 + wave) * 4 + nsub;

    int beg = 0, end = 0;
    if (node < n) {
        beg = row_ofs[node];
        end = row_ofs[node + 1];
    }

    float a0 = 0.f, a1 = 0.f, a2 = 0.f, a3 = 0.f;
    float a4 = 0.f, a5 = 0.f, a6 = 0.f, a7 = 0.f;

    for (int j = beg + e2; j < end; j += 2) {
        int s = csr_src[j];
        uint4 v = msg4[(size_t)s * 8 + fo];
        a0 += bflo(v.x); a1 += bfhi(v.x);
        a2 += bflo(v.y); a3 += bfhi(v.y);
        a4 += bflo(v.z); a5 += bfhi(v.z);
        a6 += bflo(v.w); a7 += bfhi(v.w);
    }

    a0 += __shfl_xor(a0, 8); a1 += __shfl_xor(a1, 8);
    a2 += __shfl_xor(a2, 8); a3 += __shfl_xor(a3, 8);
    a4 += __shfl_xor(a4, 8); a5 += __shfl_xor(a5, 8);
    a6 += __shfl_xor(a6, 8); a7 += __shfl_xor(a7, 8);

    if (e2 == 0 && node < n) {
        const float4 b0 = *(const float4*)(bias + fo * 8);
        const float4 b1 = *(const float4*)(bias + fo * 8 + 4);
        float v0 = a0 + b0.x, v1 = a1 + b0.y, v2 = a2 + b0.z, v3 = a3 + b0.w;
        float v4 = a4 + b1.x, v5 = a5 + b1.y, v6 = a6 + b1.z, v7 = a7 + b1.w;
        if (ACT == 0) {
            v0 = fmaxf(v0, 0.f); v1 = fmaxf(v1, 0.f);
            v2 = fmaxf(v2, 0.f); v3 = fmaxf(v3, 0.f);
            v4 = fmaxf(v4, 0.f); v5 = fmaxf(v5, 0.f);
            v6 = fmaxf(v6, 0.f); v7 = fmaxf(v7, 0.f);
        } else {
            v0 = 1.f / (1.f + __expf(-v0)); v1 = 1.f / (1.f + __expf(-v1));
            v2 = 1.f / (1.f + __expf(-v2)); v3 = 1.f / (1.f + __expf(-v3));
            v4 = 1.f / (1.f + __expf(-v4)); v5 = 1.f / (1.f + __expf(-v5));
            v6 = 1.f / (1.f + __expf(-v6)); v7 = 1.f / (1.f + __expf(-v7));
        }
        if (OUTBF) {
            uint4 u;
            u.x = pack2(v0, v1); u.y = pack2(v2, v3);
            u.z = pack2(v4, v5); u.w = pack2(v6, v7);
            *(uint4*)((unsigned short*)outv + (size_t)node * FOUT + fo * 8) = u;
        } else {
            float* op = (float*)outv + (size_t)node * FOUT + fo * 8;
            *(float4*)op = make_float4(v0, v1, v2, v3);
            *(float4*)(op + 4) = make_float4(v4, v5, v6, v7);
        }
    }
}

extern "C" void kernel_launch(void* const* d_in, const int* in_sizes, int n_in,
                              void* d_out, int out_size, void* d_ws, size_t ws_size,
                              hipStream_t stream) {
    const float* x  = (const float*)d_in[0];
    const int*   ei = (const int*)d_in[1];
    const float* W1 = (const float*)d_in[2];
    const float* b1 = (const float*)d_in[3];
    const float* W2 = (const float*)d_in[4];
    const float* b2 = (const float*)d_in[5];
    const float* W3 = (const float*)d_in[6];
    const float* b3 = (const float*)d_in[7];
    float* out = (float*)d_out;

    const int n  = in_sizes[0] / 128;   // 100000
    const int ne = in_sizes[1] / 2;     // 1600000
    const int* src = ei;
    const int* dst = ei + ne;

    const size_t feat_elems = (size_t)n * FOUT;

    // workspace layout
    unsigned short* msg16 = (unsigned short*)d_ws;              // 12.8MB bf16
    unsigned short* B16   = msg16 + feat_elems;                 // 12.8MB bf16
    int*   bins     = (int*)(B16 + feat_elems);                 // 8.4MB
    int*   gcursor  = bins + (size_t)NBUCKET * CAP;             // 511
    int*   row_ofs  = gcursor + 512;                            // n+1
    int*   csr_src  = row_ofs + n + 1;                          // ne

    const int gLin = (n + 63) / 64;
    const int gBin = (ne + CHUNK - 1) / CHUNK;   // 196
    const int gAgg = (n + 15) / 16;              // 6250 (16 nodes/block)

    // ---- CSR build (every call: ws is re-poisoned) ----
    k_init<<<1, NBUCKET, 0, stream>>>(gcursor);
    k_bin<<<gBin, 256, 0, stream>>>(src, dst, gcursor, bins, ne);
    k_csr<<<NBUCKET, 256, 0, stream>>>(gcursor, bins, row_ofs, csr_src, n);

    // ---- Layer 1 ----
    k_linear<128, 0><<<gLin, 256, 0, stream>>>(x, W1, msg16, n);
    k_agg<0, 1><<<gAgg, 256, 0, stream>>>(row_ofs, csr_src, (const uint4*)msg16, b1, B16, n);
    // ---- Layer 2 ----
    k_linear<64, 1><<<gLin, 256, 0, stream>>>(B16, W2, msg16, n);
    k_agg<0, 1><<<gAgg, 256, 0, stream>>>(row_ofs, csr_src, (const uint4*)msg16, b2, B16, n);
    // ---- Layer 3 ----
    k_linear<64, 1><<<gLin, 256, 0, stream>>>(B16, W3, msg16, n);
    k_agg<1, 0><<<gAgg, 256, 0, stream>>>(row_ofs, csr_src, (const uint4*)msg16, b3, out, n);
}